// Round 5
// baseline (342.672 us; speedup 1.0000x reference)
//
#include <hip/hip_runtime.h>
#include <hip/hip_bf16.h>

using bf16 = __hip_bfloat16;
typedef __attribute__((ext_vector_type(8))) short bf16x8;
typedef __attribute__((ext_vector_type(4))) float f32x4;

#define DECAY 0.25f

// ---------------------------------------------------------------- helpers
__device__ __forceinline__ void gload_lds16(const void* g, void* l) {
  __builtin_amdgcn_global_load_lds(
      (const __attribute__((address_space(1))) void*)g,
      (__attribute__((address_space(3))) void*)l, 16, 0, 0);
}

__device__ __forceinline__ unsigned short f2bf(float f) {
  __hip_bfloat16 h = __float2bfloat16(f);
  return *reinterpret_cast<unsigned short*>(&h);
}

// ---------------------------------------------------------------- prep kernels
__global__ void cast_x_k(const float4* __restrict__ x, ushort4* __restrict__ xb, int n4) {
  int i = blockIdx.x * blockDim.x + threadIdx.x;
  int stride = gridDim.x * blockDim.x;
  for (; i < n4; i += stride) {
    float4 v = x[i];
    ushort4 o;
    o.x = f2bf(v.x); o.y = f2bf(v.y); o.z = f2bf(v.z); o.w = f2bf(v.w);
    xb[i] = o;
  }
}

__global__ void transpose_cast_k(const float* __restrict__ w, bf16* __restrict__ wt, int N) {
  __shared__ float t[32][33];
  int bx = blockIdx.x * 32, by = blockIdx.y * 32;
  int tx = threadIdx.x, ty = threadIdx.y;  // block (32,8)
#pragma unroll
  for (int i = 0; i < 32; i += 8)
    t[ty + i][tx] = w[(size_t)(by + ty + i) * N + bx + tx];
  __syncthreads();
#pragma unroll
  for (int i = 0; i < 32; i += 8)
    wt[(size_t)(bx + ty + i) * N + by + tx] = __float2bfloat16(t[tx][ty + i]);
}

// ---------------------------------------------------------------- 128x128 GEMM, 4 blocks/CU
// C[M][N] = A[M][K] * BT[N][K]^T (+bias; EPI=1: residual). m97 2-barrier... 1-barrier
// double-buffered structure; TLP (4 independent blocks/CU) hides the barrier drain.
// FRAGMENT-MAJOR planes (0 bank conflicts, verified R3):
//   plane byte d = f*1024 + l*16 holds src[row0+f*16+(l&15)][k0+(l>>4)*8 ..+8]
// LDS 2 x (A 8KB | B 8KB) = 32KB. Grid 1024 1-D, m204 bijective XCD swizzle.

__device__ __forceinline__ void stage_plane128(const bf16* __restrict__ src, int ldk,
                                               int row0, int k0, char* plane, int tid) {
#pragma unroll
  for (int u = 0; u < 2; ++u) {
    int d = tid * 16 + u * 4096;
    int f = d >> 10;
    int l = (d >> 4) & 63;
    const bf16* g = src + (size_t)(row0 + f * 16 + (l & 15)) * ldk + k0 + (l >> 4) * 8;
    gload_lds16(g, plane + d);
  }
}

template <int EPI, typename OutT>
__global__ __launch_bounds__(256, 4) void gemm128_k(
    const bf16* __restrict__ A, const bf16* __restrict__ BT,
    OutT* __restrict__ C, const float* __restrict__ bias,
    const float* __restrict__ xres, const float* __restrict__ alpha_p,
    int M, int N, int K, int TN) {
  __shared__ char lds[32768];
  const int tid = threadIdx.x;
  const int lane = tid & 63;
  const int w = tid >> 6;
  const int wr = w >> 1, wc = w & 1;  // 2x2 waves, per-wave 64x64 out
  // bijective XCD swizzle (m204; nwg%8==0): each XCD gets a contiguous vid chunk
  const int nwg = gridDim.x;
  const int vid = (blockIdx.x & 7) * (nwg >> 3) + (blockIdx.x >> 3);
  const int tm = (vid / TN) * 128;
  const int tn = (vid % TN) * 128;
  const int ro = lane * 16;
  const int NT = K >> 5;

  f32x4 acc[4][4] = {};

  stage_plane128(A,  K, tm, 0, lds + 0,    tid);
  stage_plane128(BT, K, tn, 0, lds + 8192, tid);
  __syncthreads();

  for (int t = 0; t < NT; ++t) {
    const char* cb = lds + (t & 1) * 16384;
    char* nb = lds + ((t + 1) & 1) * 16384;
    if (t + 1 < NT) {  // block-uniform
      stage_plane128(A,  K, tm, (t + 1) * 32, nb, tid);
      stage_plane128(BT, K, tn, (t + 1) * 32, nb + 8192, tid);
    }
    bf16x8 a[4], b[4];
#pragma unroll
    for (int i = 0; i < 4; ++i) a[i] = *(const bf16x8*)(cb + (wr * 4 + i) * 1024 + ro);
#pragma unroll
    for (int j = 0; j < 4; ++j) b[j] = *(const bf16x8*)(cb + 8192 + (wc * 4 + j) * 1024 + ro);
#pragma unroll
    for (int i = 0; i < 4; ++i)
#pragma unroll
      for (int j = 0; j < 4; ++j)
        acc[i][j] = __builtin_amdgcn_mfma_f32_16x16x32_bf16(a[i], b[j], acc[i][j], 0, 0, 0);
    __syncthreads();  // drains vmcnt(0): stage(t+1) landed; cb rewritten only at t+2
  }

  // epilogue: C/D layout col=lane&15, row=(lane>>4)*4+r  [m89]
  float alpha = 0.f;
  if constexpr (EPI) alpha = *alpha_p;
#pragma unroll
  for (int i = 0; i < 4; ++i) {
    int m0 = tm + wr * 64 + i * 16 + (lane >> 4) * 4;
#pragma unroll
    for (int j = 0; j < 4; ++j) {
      int n = tn + wc * 64 + j * 16 + (lane & 15);
      float bb = bias[n];
#pragma unroll
      for (int r = 0; r < 4; ++r) {
        size_t idx = (size_t)(m0 + r) * N + n;
        float v = acc[i][j][r] + bb;
        if constexpr (EPI) v = xres[idx] + alpha * v;
        if constexpr (__is_same(OutT, bf16)) C[idx] = __float2bfloat16(v);
        else                                 C[idx] = v;
      }
    }
  }
}

// ---------------------------------------------------------------- chunked LIF scan (bf16 in)
__global__ void snn_scan_k(const bf16* __restrict__ xp, bf16* __restrict__ sp,
                           const float* __restrict__ thre_p,
                           int T, int H, int CHUNK, int WARM) {
  int h = blockIdx.x * blockDim.x + threadIdx.x;
  int b = blockIdx.y;
  int c = blockIdx.z;
  float thre = *thre_p;
  float l1 = thre, l2 = 2.f * thre, l3 = 3.f * thre, l4 = 4.f * thre;
  int t0 = c * CHUNK;
  int tw = t0 - WARM;
  if (tw < 0) tw = 0;
  const bf16* xcol = xp + (size_t)b * T * H + h;
  bf16* scol = sp + (size_t)b * T * H + h;
  float mem = 0.f;
  for (int t = tw; t < t0; ++t) {  // warmup (state error ~0.25^WARM)
    float xv = __bfloat162float(xcol[(size_t)t * H]);
    mem = DECAY * mem + xv;
    float s = (float)((mem >= l1) + (mem >= l2) + (mem >= l3) + (mem >= l4));
    mem -= s * thre;
  }
  for (int t = t0; t < t0 + CHUNK; ++t) {
    float xv = __bfloat162float(xcol[(size_t)t * H]);
    mem = DECAY * mem + xv;
    float s = (float)((mem >= l1) + (mem >= l2) + (mem >= l3) + (mem >= l4));
    mem -= s * thre;
    scol[(size_t)t * H] = __float2bfloat16(s);  // 0..4 exact in bf16
  }
}

// ---------------------------------------------------------------- launch
extern "C" void kernel_launch(void* const* d_in, const int* in_sizes, int n_in,
                              void* d_out, int out_size, void* d_ws, size_t ws_size,
                              hipStream_t stream) {
  const float* x     = (const float*)d_in[0];
  const float* alpha = (const float*)d_in[1];
  const float* thre  = (const float*)d_in[2];
  const float* w_in  = (const float*)d_in[3];
  const float* b_in  = (const float*)d_in[4];
  const float* w_out = (const float*)d_in[5];
  const float* b_out = (const float*)d_in[6];
  float* out = (float*)d_out;

  const int B = 4, T = 2048, H = 2048;
  const int M = B * T;  // 8192
  const int K = H, N = H;

  char* ws = (char*)d_ws;
  bf16* xb     = (bf16*)(ws);
  bf16* spikes = (bf16*)(ws);  // alias: xb dead after GEMM1
  bf16* w_inT  = (bf16*)(ws + (size_t)M * K * 2);
  bf16* w_outT = (bf16*)(ws + (size_t)M * K * 2 + (size_t)K * N * 2);
  bf16* xp     = (bf16*)(ws + (size_t)M * K * 2 + (size_t)2 * K * N * 2);

  cast_x_k<<<2048, 256, 0, stream>>>((const float4*)x, (ushort4*)xb, M * K / 4);
  dim3 tb(32, 8);
  dim3 tg(N / 32, K / 32);
  transpose_cast_k<<<tg, tb, 0, stream>>>(w_in, w_inT, N);
  transpose_cast_k<<<tg, tb, 0, stream>>>(w_out, w_outT, N);

  const int TN = N / 128;                 // 16
  const int NWG = (M / 128) * TN;         // 1024
  gemm128_k<0, bf16><<<NWG, 256, 0, stream>>>(xb, w_inT, xp, b_in, nullptr, nullptr, M, N, K, TN);

  const int CHUNK = 128, WARM = 32, NC = T / CHUNK;
  dim3 sg(H / 256, B, NC);
  snn_scan_k<<<sg, 256, 0, stream>>>(xp, spikes, thre, T, H, CHUNK, WARM);

  gemm128_k<1, float><<<NWG, 256, 0, stream>>>(spikes, w_outT, out, b_out, x, alpha, M, N, K, TN);
}

// Round 6
// 237.991 us; speedup vs baseline: 1.4399x; 1.4399x over previous
//
#include <hip/hip_runtime.h>
#include <hip/hip_bf16.h>

using bf16 = __hip_bfloat16;
typedef __attribute__((ext_vector_type(8))) short bf16x8;
typedef __attribute__((ext_vector_type(4))) float f32x4;

#define DECAY 0.25f

// ---------------------------------------------------------------- helpers
__device__ __forceinline__ void gload_lds16(const void* g, void* l) {
  __builtin_amdgcn_global_load_lds(
      (const __attribute__((address_space(1))) void*)g,
      (__attribute__((address_space(3))) void*)l, 16, 0, 0);
}

// compiler-only memory fence (no instruction, no wait forced)
#define CFENCE() asm volatile("" ::: "memory")
#define VMCNT4() asm volatile("s_waitcnt vmcnt(4)" ::: "memory")

__device__ __forceinline__ unsigned short f2bf(float f) {
  __hip_bfloat16 h = __float2bfloat16(f);
  return *reinterpret_cast<unsigned short*>(&h);
}

// ---------------------------------------------------------------- prep kernels
__global__ void cast_x_k(const float4* __restrict__ x, ushort4* __restrict__ xb, int n4) {
  int i = blockIdx.x * blockDim.x + threadIdx.x;
  int stride = gridDim.x * blockDim.x;
  for (; i < n4; i += stride) {
    float4 v = x[i];
    ushort4 o;
    o.x = f2bf(v.x); o.y = f2bf(v.y); o.z = f2bf(v.z); o.w = f2bf(v.w);
    xb[i] = o;
  }
}

__global__ void transpose_cast_k(const float* __restrict__ w, bf16* __restrict__ wt, int N) {
  __shared__ float t[32][33];
  int bx = blockIdx.x * 32, by = blockIdx.y * 32;
  int tx = threadIdx.x, ty = threadIdx.y;  // block (32,8)
#pragma unroll
  for (int i = 0; i < 32; i += 8)
    t[ty + i][tx] = w[(size_t)(by + ty + i) * N + bx + tx];
  __syncthreads();
#pragma unroll
  for (int i = 0; i < 32; i += 8)
    wt[(size_t)(bx + ty + i) * N + by + tx] = __float2bfloat16(t[tx][ty + i]);
}

// ---------------------------------------------------------------- 256x256 GEMM, 4 fine phases/tile
// C[M][N] = A[M][K] * BT[N][K]^T (+bias; EPI=1: residual). 8 waves 2Mx4N, per-wave 128x64.
// LDS per 64KB buffer: A_kl@0, A_kr@16384, B_kl@32768, B_kr@49152 (16KB planes,
// FRAGMENT-MAJOR: plane byte d = f*1024 + l*16 holds src[row0+f*16+(l&15)][k0+(l>>4)*8..+8];
// 0 bank conflicts, verified R3). 2 buffers.
//
// Schedule per K64-tile t: 4 phases (kh, mh), each {stage 1 plane(t+1), read 4-8 frags
// [compiler counted lgkmcnt], 16 MFMA, fence, [vmcnt(4) at p1/p3], s_barrier}.
// 1 barrier/phase: next phase's read-issue overlaps prior phase's MFMA drain.
// vmcnt ledger: end-p1 drains kr(t) stages (issued p2/p3 of t-1); end-p3 drains
// kl(t+1) (issued p0/p1 of t). Barrier after each vmcnt publishes cross-wave.

__device__ __forceinline__ void stage_plane(const bf16* __restrict__ src, int ldk,
                                            int row0, int k0, char* plane, int tid) {
#pragma unroll
  for (int u = 0; u < 2; ++u) {
    int d = tid * 16 + u * 8192;
    int f = d >> 10;
    int l = (d >> 4) & 63;
    const bf16* g = src + (size_t)(row0 + f * 16 + (l & 15)) * ldk + k0 + (l >> 4) * 8;
    gload_lds16(g, plane + d);
  }
}

__device__ __forceinline__ void mfma16(const bf16x8 (&a)[4], const bf16x8 (&b)[4],
                                       f32x4 (&acc)[8][4], int mh) {
#pragma unroll
  for (int i = 0; i < 4; ++i)
#pragma unroll
    for (int j = 0; j < 4; ++j)
      acc[mh * 4 + i][j] =
          __builtin_amdgcn_mfma_f32_16x16x32_bf16(a[i], b[j], acc[mh * 4 + i][j], 0, 0, 0);
}

template <int EPI, typename OutT>
__global__ __launch_bounds__(512, 1) void gemm256_k(
    const bf16* __restrict__ A, const bf16* __restrict__ BT,
    OutT* __restrict__ C, const float* __restrict__ bias,
    const float* __restrict__ xres, const float* __restrict__ alpha_p,
    int M, int N, int K, int TM) {
  __shared__ char lds[131072];
  const int tid = threadIdx.x;
  const int lane = tid & 63;
  const int w = tid >> 6;
  const int wr = w >> 2, wc = w & 3;  // 2M x 4N waves, per-wave 128x64 out
  // m204 bijective XCD swizzle (nwg%8==0), m-fast: XCD x owns one n-slab (L2-resident B)
  const int nwg = gridDim.x;
  const int vid = (blockIdx.x & 7) * (nwg >> 3) + (blockIdx.x >> 3);
  const int tm = (vid % TM) * 256;
  const int tn = (vid / TM) * 256;
  const int ro = lane * 16;
  const int NT = K >> 6;

  f32x4 acc[8][4] = {};

  // prologue: tile0's 4 planes; wait kl(0) (newest 4 = Akr0,Bkr0 stay in flight)
  stage_plane(A,  K, tm, 0,  lds + 0,     tid);
  stage_plane(BT, K, tn, 0,  lds + 32768, tid);
  stage_plane(A,  K, tm, 32, lds + 16384, tid);
  stage_plane(BT, K, tn, 32, lds + 49152, tid);
  CFENCE();
  VMCNT4();
  __builtin_amdgcn_s_barrier();

  for (int t = 0; t < NT; ++t) {
    const char* cb = lds + (t & 1) * 65536;
    char* nb = lds + ((t + 1) & 1) * 65536;
    const int k1 = (t + 1 < NT ? t + 1 : NT - 1) * 64;
    const char* pa = cb + wr * 8192;
    const char* pb = cb + 32768 + wc * 4096;
    bf16x8 a[4], b[4];

    // ---- p0 (kl, mh0); stage A_kl(t+1)
    stage_plane(A, K, tm, k1, nb + 0, tid);
#pragma unroll
    for (int j = 0; j < 4; ++j) b[j] = *(const bf16x8*)(pb + j * 1024 + ro);
#pragma unroll
    for (int i = 0; i < 4; ++i) a[i] = *(const bf16x8*)(pa + i * 1024 + ro);
    __builtin_amdgcn_s_setprio(1);
    mfma16(a, b, acc, 0);
    __builtin_amdgcn_s_setprio(0);
    CFENCE();
    __builtin_amdgcn_s_barrier();

    // ---- p1 (kl, mh1); stage B_kl(t+1)
    stage_plane(BT, K, tn, k1, nb + 32768, tid);
#pragma unroll
    for (int i = 0; i < 4; ++i) a[i] = *(const bf16x8*)(pa + 4096 + i * 1024 + ro);
    __builtin_amdgcn_s_setprio(1);
    mfma16(a, b, acc, 1);
    __builtin_amdgcn_s_setprio(0);
    CFENCE();
    VMCNT4();                 // kr(t) landed (staged p2/p3 of t-1)
    __builtin_amdgcn_s_barrier();

    // ---- p2 (kr, mh0); stage A_kr(t+1)
    stage_plane(A, K, tm, k1 + 32, nb + 16384, tid);
#pragma unroll
    for (int j = 0; j < 4; ++j) b[j] = *(const bf16x8*)(pb + 16384 + j * 1024 + ro);
#pragma unroll
    for (int i = 0; i < 4; ++i) a[i] = *(const bf16x8*)(pa + 16384 + i * 1024 + ro);
    __builtin_amdgcn_s_setprio(1);
    mfma16(a, b, acc, 0);
    __builtin_amdgcn_s_setprio(0);
    CFENCE();
    __builtin_amdgcn_s_barrier();

    // ---- p3 (kr, mh1); stage B_kr(t+1)
    stage_plane(BT, K, tn, k1 + 32, nb + 49152, tid);
#pragma unroll
    for (int i = 0; i < 4; ++i) a[i] = *(const bf16x8*)(pa + 16384 + 4096 + i * 1024 + ro);
    __builtin_amdgcn_s_setprio(1);
    mfma16(a, b, acc, 1);
    __builtin_amdgcn_s_setprio(0);
    CFENCE();
    VMCNT4();                 // kl(t+1) landed (staged p0/p1 of t)
    __builtin_amdgcn_s_barrier();
  }

  // epilogue: C/D layout col=lane&15, row=(lane>>4)*4+r  [m89]
  float alpha = 0.f;
  if constexpr (EPI) alpha = *alpha_p;
#pragma unroll
  for (int i = 0; i < 8; ++i) {
    int m0 = tm + wr * 128 + i * 16 + (lane >> 4) * 4;
#pragma unroll
    for (int j = 0; j < 4; ++j) {
      int n = tn + wc * 64 + j * 16 + (lane & 15);
      float bb = bias[n];
#pragma unroll
      for (int r = 0; r < 4; ++r) {
        size_t idx = (size_t)(m0 + r) * N + n;
        float v = acc[i][j][r] + bb;
        if constexpr (EPI) v = xres[idx] + alpha * v;
        if constexpr (__is_same(OutT, bf16)) C[idx] = __float2bfloat16(v);
        else                                 C[idx] = v;
      }
    }
  }
}

// ---------------------------------------------------------------- chunked LIF scan (bf16 in)
__global__ void snn_scan_k(const bf16* __restrict__ xp, bf16* __restrict__ sp,
                           const float* __restrict__ thre_p,
                           int T, int H, int CHUNK, int WARM) {
  int h = blockIdx.x * blockDim.x + threadIdx.x;
  int b = blockIdx.y;
  int c = blockIdx.z;
  float thre = *thre_p;
  float l1 = thre, l2 = 2.f * thre, l3 = 3.f * thre, l4 = 4.f * thre;
  int t0 = c * CHUNK;
  int tw = t0 - WARM;
  if (tw < 0) tw = 0;
  const bf16* xcol = xp + (size_t)b * T * H + h;
  bf16* scol = sp + (size_t)b * T * H + h;
  float mem = 0.f;
  for (int t = tw; t < t0; ++t) {  // warmup (state error ~0.25^WARM)
    float xv = __bfloat162float(xcol[(size_t)t * H]);
    mem = DECAY * mem + xv;
    float s = (float)((mem >= l1) + (mem >= l2) + (mem >= l3) + (mem >= l4));
    mem -= s * thre;
  }
  for (int t = t0; t < t0 + CHUNK; ++t) {
    float xv = __bfloat162float(xcol[(size_t)t * H]);
    mem = DECAY * mem + xv;
    float s = (float)((mem >= l1) + (mem >= l2) + (mem >= l3) + (mem >= l4));
    mem -= s * thre;
    scol[(size_t)t * H] = __float2bfloat16(s);  // 0..4 exact in bf16
  }
}

// ---------------------------------------------------------------- launch
extern "C" void kernel_launch(void* const* d_in, const int* in_sizes, int n_in,
                              void* d_out, int out_size, void* d_ws, size_t ws_size,
                              hipStream_t stream) {
  const float* x     = (const float*)d_in[0];
  const float* alpha = (const float*)d_in[1];
  const float* thre  = (const float*)d_in[2];
  const float* w_in  = (const float*)d_in[3];
  const float* b_in  = (const float*)d_in[4];
  const float* w_out = (const float*)d_in[5];
  const float* b_out = (const float*)d_in[6];
  float* out = (float*)d_out;

  const int B = 4, T = 2048, H = 2048;
  const int M = B * T;  // 8192
  const int K = H, N = H;

  char* ws = (char*)d_ws;
  bf16* xb     = (bf16*)(ws);
  bf16* spikes = (bf16*)(ws);  // alias: xb dead after GEMM1
  bf16* w_inT  = (bf16*)(ws + (size_t)M * K * 2);
  bf16* w_outT = (bf16*)(ws + (size_t)M * K * 2 + (size_t)K * N * 2);
  bf16* xp     = (bf16*)(ws + (size_t)M * K * 2 + (size_t)2 * K * N * 2);

  cast_x_k<<<2048, 256, 0, stream>>>((const float4*)x, (ushort4*)xb, M * K / 4);
  dim3 tb(32, 8);
  dim3 tg(N / 32, K / 32);
  transpose_cast_k<<<tg, tb, 0, stream>>>(w_in, w_inT, N);
  transpose_cast_k<<<tg, tb, 0, stream>>>(w_out, w_outT, N);

  const int TM = M / 256;                 // 32
  const int NWG = TM * (N / 256);         // 256
  gemm256_k<0, bf16><<<NWG, 512, 0, stream>>>(xb, w_inT, xp, b_in, nullptr, nullptr, M, N, K, TM);

  const int CHUNK = 128, WARM = 32, NC = T / CHUNK;
  dim3 sg(H / 256, B, NC);
  snn_scan_k<<<sg, 256, 0, stream>>>(xp, spikes, thre, T, H, CHUNK, WARM);

  gemm256_k<1, float><<<NWG, 512, 0, stream>>>(spikes, w_outT, out, b_out, x, alpha, M, N, K, TM);
}